// Round 3
// baseline (296.805 us; speedup 1.0000x reference)
//
#include <hip/hip_runtime.h>
#include <math.h>

#define NBINS 4
#define SLOTS 64   // atomic-spread slots per bin

// ws layout: float ss[NBINS][SLOTS], then uint cnt[NBINS][SLOTS]
// bin edges: log1p([0,5,25,50,100]) in float32

// Each "tile" = 512 float4s (block of 256 threads, 2 float4s/thread/input).
#define TILE_F4 512

__global__ __launch_bounds__(256) void qrmse_bins(
    const float4* __restrict__ yp4, const float4* __restrict__ yt4,
    const float* __restrict__ yp, const float* __restrict__ yt,
    float* __restrict__ g_ss, unsigned int* __restrict__ g_cnt,
    int n4, int n, int total_tiles)
{
    const float B1 = 1.7917594909667969f;   // log1p(5)  in f32
    const float B2 = 3.2580965518951416f;   // log1p(25)
    const float B3 = 3.9318256378173828f;   // log1p(50)
    const float B4 = 4.6151204109191895f;   // log1p(100)

    float ss0 = 0.f, ss1 = 0.f, ss2 = 0.f, ss3 = 0.f;
    unsigned int c0 = 0, c1 = 0, c2 = 0, c3 = 0;

#define ACC(PC, TC)                                          \
    {                                                        \
        float d  = (PC) - (TC);                              \
        float sq = d * d;                                    \
        float tv = (TC);                                     \
        bool b0 = (tv >= 0.f) & (tv < B1);                   \
        bool b1 = (tv >= B1)  & (tv < B2);                   \
        bool b2 = (tv >= B2)  & (tv < B3);                   \
        bool b3 = (tv >= B3)  & (tv < B4);                   \
        ss0 += b0 ? sq : 0.f;  c0 += b0;                     \
        ss1 += b1 ? sq : 0.f;  c1 += b1;                     \
        ss2 += b2 ? sq : 0.f;  c2 += b2;                     \
        ss3 += b3 ? sq : 0.f;  c3 += b3;                     \
    }
#define ACC4(P0, P1, T0, T1)                                 \
    {                                                        \
        ACC(P0.x, T0.x); ACC(P0.y, T0.y);                    \
        ACC(P0.z, T0.z); ACC(P0.w, T0.w);                    \
        ACC(P1.x, T1.x); ACC(P1.y, T1.y);                    \
        ACC(P1.z, T1.z); ACC(P1.w, T1.w);                    \
    }

    const int tid = threadIdx.x;
    const int b   = blockIdx.x;
    const int G   = gridDim.x;

    // ragged exact partition of tiles over blocks — NO per-load bounds checks
    const int base    = total_tiles / G;
    const int extra   = total_tiles % G;
    const int myStart = b * base + (b < extra ? b : extra);
    const int myCnt   = base + (b < extra ? 1 : 0);

    if (myCnt > 0) {
        const float4* Pp = yp4 + myStart * TILE_F4 + tid;
        const float4* Tp = yt4 + myStart * TILE_F4 + tid;

        float4 pa0, pa1, ta0, ta1;   // ping
        float4 pb0, pb1, tb0, tb1;   // pong

        // prime: tile 0
        pa0 = Pp[0]; pa1 = Pp[256];
        ta0 = Tp[0]; ta1 = Tp[256];

        int it = 1;
        // ping-pong, 2 tiles per trip, no register copies
        for (; it + 1 < myCnt; it += 2) {
            Pp += TILE_F4; Tp += TILE_F4;
            pb0 = Pp[0]; pb1 = Pp[256];
            tb0 = Tp[0]; tb1 = Tp[256];
            __builtin_amdgcn_sched_barrier(0);   // keep prefetch above compute
            ACC4(pa0, pa1, ta0, ta1);

            Pp += TILE_F4; Tp += TILE_F4;
            pa0 = Pp[0]; pa1 = Pp[256];
            ta0 = Tp[0]; ta1 = Tp[256];
            __builtin_amdgcn_sched_barrier(0);
            ACC4(pb0, pb1, tb0, tb1);
        }
        if (it < myCnt) {
            // one more tile: prefetch it, compute ping, then compute it
            Pp += TILE_F4; Tp += TILE_F4;
            pb0 = Pp[0]; pb1 = Pp[256];
            tb0 = Tp[0]; tb1 = Tp[256];
            __builtin_amdgcn_sched_barrier(0);
            ACC4(pa0, pa1, ta0, ta1);
            ACC4(pb0, pb1, tb0, tb1);
        } else {
            ACC4(pa0, pa1, ta0, ta1);
        }
    }

    // leftovers (sub-tile float4s + scalar tail) — block 0, guarded (tiny)
    if (b == 0) {
        for (int i = total_tiles * TILE_F4 + tid; i < n4; i += 256) {
            float4 p = yp4[i];
            float4 t = yt4[i];
            ACC(p.x, t.x); ACC(p.y, t.y); ACC(p.z, t.z); ACC(p.w, t.w);
        }
        if (tid == 0) {
            for (int i = n4 * 4; i < n; ++i) {
                float pp = yp[i];
                float tt = yt[i];
                ACC(pp, tt);
            }
        }
    }
#undef ACC4
#undef ACC

    // wave-64 shuffle reduction
    for (int off = 32; off > 0; off >>= 1) {
        ss0 += __shfl_down(ss0, off);
        ss1 += __shfl_down(ss1, off);
        ss2 += __shfl_down(ss2, off);
        ss3 += __shfl_down(ss3, off);
        c0  += __shfl_down(c0,  off);
        c1  += __shfl_down(c1,  off);
        c2  += __shfl_down(c2,  off);
        c3  += __shfl_down(c3,  off);
    }

    __shared__ float        s_ss[4][NBINS];
    __shared__ unsigned int s_cnt[4][NBINS];
    const int lane = tid & 63;
    const int wave = tid >> 6;
    if (lane == 0) {
        s_ss[wave][0] = ss0; s_ss[wave][1] = ss1;
        s_ss[wave][2] = ss2; s_ss[wave][3] = ss3;
        s_cnt[wave][0] = c0; s_cnt[wave][1] = c1;
        s_cnt[wave][2] = c2; s_cnt[wave][3] = c3;
    }
    __syncthreads();

    if (tid == 0) {
        const int slot = b & (SLOTS - 1);
#pragma unroll
        for (int bin = 0; bin < NBINS; ++bin) {
            float bs = s_ss[0][bin] + s_ss[1][bin] + s_ss[2][bin] + s_ss[3][bin];
            unsigned int bc = s_cnt[0][bin] + s_cnt[1][bin] + s_cnt[2][bin] + s_cnt[3][bin];
            atomicAdd(&g_ss[bin * SLOTS + slot], bs);
            atomicAdd(&g_cnt[bin * SLOTS + slot], bc);
        }
    }
}

__global__ __launch_bounds__(64) void qrmse_final(
    const float* __restrict__ g_ss,
    const unsigned int* __restrict__ g_cnt,
    float* __restrict__ out)
{
    const int lane = threadIdx.x;  // 64 lanes, one per slot
    float ssb[NBINS];
    unsigned int cb[NBINS];
#pragma unroll
    for (int b = 0; b < NBINS; ++b) {
        ssb[b] = g_ss[b * SLOTS + lane];
        cb[b]  = g_cnt[b * SLOTS + lane];
    }
    for (int off = 32; off > 0; off >>= 1) {
#pragma unroll
        for (int b = 0; b < NBINS; ++b) {
            ssb[b] += __shfl_down(ssb[b], off);
            cb[b]  += __shfl_down(cb[b],  off);
        }
    }
    if (lane == 0) {
        float wsum = 0.f;
        float mse[NBINS], w[NBINS];
        bool any = false;
#pragma unroll
        for (int b = 0; b < NBINS; ++b) {
            bool present = (cb[b] > 0);
            any |= present;
            float csafe = present ? (float)cb[b] : 1.0f;
            mse[b] = ssb[b] / csafe;
            w[b] = present ? (1.0f / csafe) : 0.0f;
            wsum += w[b];
        }
        float denom = (wsum > 0.f) ? wsum : 1.0f;
        float wmse = 0.f;
#pragma unroll
        for (int b = 0; b < NBINS; ++b) wmse += (w[b] / denom) * mse[b];
        out[0] = any ? sqrtf(wmse + 1e-8f) : 0.0f;
    }
}

extern "C" void kernel_launch(void* const* d_in, const int* in_sizes, int n_in,
                              void* d_out, int out_size, void* d_ws, size_t ws_size,
                              hipStream_t stream) {
    const float* yp = (const float*)d_in[0];
    const float* yt = (const float*)d_in[1];
    float* out = (float*)d_out;

    float* g_ss = (float*)d_ws;                                   // 4*64 floats
    unsigned int* g_cnt = (unsigned int*)d_ws + NBINS * SLOTS;    // 4*64 uints

    int n  = in_sizes[0];
    int n4 = n / 4;
    int total_tiles = n4 / TILE_F4;   // whole tiles; remainder done by block 0

    hipMemsetAsync(d_ws, 0, 2 * NBINS * SLOTS * sizeof(float), stream);

    const int block = 256;
    const int grid  = 2048;  // 2048 blocks * 4 waves = 8192 waves = full device
    qrmse_bins<<<grid, block, 0, stream>>>(
        (const float4*)yp, (const float4*)yt, yp, yt, g_ss, g_cnt,
        n4, n, total_tiles);
    qrmse_final<<<1, 64, 0, stream>>>(g_ss, g_cnt, out);
}

// Round 4
// 289.472 us; speedup vs baseline: 1.0253x; 1.0253x over previous
//
#include <hip/hip_runtime.h>
#include <math.h>

#define NBINS 4
#define SLOTS 64   // atomic-spread slots per bin

// ws layout: float ss[NBINS][SLOTS], then uint cnt[NBINS][SLOTS]
// bin edges: log1p([0,5,25,50,100]) in float32

// Each block consumes CHUNK_F4 consecutive float4s from EACH input:
// 256 threads x 4 float4s, all 8 loads (2 inputs) hoisted, guard-free.
#define CHUNK_F4 1024

__global__ __launch_bounds__(256) void qrmse_bins(
    const float4* __restrict__ yp4, const float4* __restrict__ yt4,
    const float* __restrict__ yp, const float* __restrict__ yt,
    float* __restrict__ g_ss, unsigned int* __restrict__ g_cnt,
    int n4, int n, int full_blocks)
{
    const float B1 = 1.7917594909667969f;   // log1p(5)  in f32
    const float B2 = 3.2580965518951416f;   // log1p(25)
    const float B3 = 3.9318256378173828f;   // log1p(50)
    const float B4 = 4.6151204109191895f;   // log1p(100)

    float ss0 = 0.f, ss1 = 0.f, ss2 = 0.f, ss3 = 0.f;
    unsigned int c0 = 0, c1 = 0, c2 = 0, c3 = 0;

#define ACC(PC, TC)                                          \
    {                                                        \
        float d  = (PC) - (TC);                              \
        float sq = d * d;                                    \
        float tv = (TC);                                     \
        bool b0 = (tv >= 0.f) & (tv < B1);                   \
        bool b1 = (tv >= B1)  & (tv < B2);                   \
        bool b2 = (tv >= B2)  & (tv < B3);                   \
        bool b3 = (tv >= B3)  & (tv < B4);                   \
        ss0 += b0 ? sq : 0.f;  c0 += b0;                     \
        ss1 += b1 ? sq : 0.f;  c1 += b1;                     \
        ss2 += b2 ? sq : 0.f;  c2 += b2;                     \
        ss3 += b3 ? sq : 0.f;  c3 += b3;                     \
    }
#define ACCF4(P, T)                                          \
    { ACC(P.x, T.x); ACC(P.y, T.y); ACC(P.z, T.z); ACC(P.w, T.w); }

    const int tid = threadIdx.x;
    const int b   = blockIdx.x;

    if (b < full_blocks) {
        // guard-free hot path: 8 independent 16B loads, no bounds checks
        const float4* P = yp4 + (size_t)b * CHUNK_F4 + tid;
        const float4* T = yt4 + (size_t)b * CHUNK_F4 + tid;
        float4 p0 = P[0], p1 = P[256], p2 = P[512], p3 = P[768];
        float4 t0 = T[0], t1 = T[256], t2 = T[512], t3 = T[768];
        ACCF4(p0, t0); ACCF4(p1, t1); ACCF4(p2, t2); ACCF4(p3, t3);
    } else {
        // ragged last block (empty when n4 % CHUNK_F4 == 0)
        for (int i = full_blocks * CHUNK_F4 + tid; i < n4; i += 256) {
            float4 p = yp4[i];
            float4 t = yt4[i];
            ACCF4(p, t);
        }
        // scalar tail (n % 4)
        if (tid == 0) {
            for (int i = n4 * 4; i < n; ++i) {
                float pp = yp[i];
                float tt = yt[i];
                ACC(pp, tt);
            }
        }
    }
#undef ACCF4
#undef ACC

    // wave-64 shuffle reduction
    for (int off = 32; off > 0; off >>= 1) {
        ss0 += __shfl_down(ss0, off);
        ss1 += __shfl_down(ss1, off);
        ss2 += __shfl_down(ss2, off);
        ss3 += __shfl_down(ss3, off);
        c0  += __shfl_down(c0,  off);
        c1  += __shfl_down(c1,  off);
        c2  += __shfl_down(c2,  off);
        c3  += __shfl_down(c3,  off);
    }

    __shared__ float        s_ss[4][NBINS];
    __shared__ unsigned int s_cnt[4][NBINS];
    const int lane = tid & 63;
    const int wave = tid >> 6;
    if (lane == 0) {
        s_ss[wave][0] = ss0; s_ss[wave][1] = ss1;
        s_ss[wave][2] = ss2; s_ss[wave][3] = ss3;
        s_cnt[wave][0] = c0; s_cnt[wave][1] = c1;
        s_cnt[wave][2] = c2; s_cnt[wave][3] = c3;
    }
    __syncthreads();

    if (tid == 0) {
        const int slot = b & (SLOTS - 1);
#pragma unroll
        for (int bin = 0; bin < NBINS; ++bin) {
            float bs = s_ss[0][bin] + s_ss[1][bin] + s_ss[2][bin] + s_ss[3][bin];
            unsigned int bc = s_cnt[0][bin] + s_cnt[1][bin] + s_cnt[2][bin] + s_cnt[3][bin];
            atomicAdd(&g_ss[bin * SLOTS + slot], bs);
            atomicAdd(&g_cnt[bin * SLOTS + slot], bc);
        }
    }
}

__global__ __launch_bounds__(64) void qrmse_final(
    const float* __restrict__ g_ss,
    const unsigned int* __restrict__ g_cnt,
    float* __restrict__ out)
{
    const int lane = threadIdx.x;  // 64 lanes, one per slot
    float ssb[NBINS];
    unsigned int cb[NBINS];
#pragma unroll
    for (int b = 0; b < NBINS; ++b) {
        ssb[b] = g_ss[b * SLOTS + lane];
        cb[b]  = g_cnt[b * SLOTS + lane];
    }
    for (int off = 32; off > 0; off >>= 1) {
#pragma unroll
        for (int b = 0; b < NBINS; ++b) {
            ssb[b] += __shfl_down(ssb[b], off);
            cb[b]  += __shfl_down(cb[b],  off);
        }
    }
    if (lane == 0) {
        float wsum = 0.f;
        float mse[NBINS], w[NBINS];
        bool any = false;
#pragma unroll
        for (int b = 0; b < NBINS; ++b) {
            bool present = (cb[b] > 0);
            any |= present;
            float csafe = present ? (float)cb[b] : 1.0f;
            mse[b] = ssb[b] / csafe;
            w[b] = present ? (1.0f / csafe) : 0.0f;
            wsum += w[b];
        }
        float denom = (wsum > 0.f) ? wsum : 1.0f;
        float wmse = 0.f;
#pragma unroll
        for (int b = 0; b < NBINS; ++b) wmse += (w[b] / denom) * mse[b];
        out[0] = any ? sqrtf(wmse + 1e-8f) : 0.0f;
    }
}

extern "C" void kernel_launch(void* const* d_in, const int* in_sizes, int n_in,
                              void* d_out, int out_size, void* d_ws, size_t ws_size,
                              hipStream_t stream) {
    const float* yp = (const float*)d_in[0];
    const float* yt = (const float*)d_in[1];
    float* out = (float*)d_out;

    float* g_ss = (float*)d_ws;                                   // 4*64 floats
    unsigned int* g_cnt = (unsigned int*)d_ws + NBINS * SLOTS;    // 4*64 uints

    int n  = in_sizes[0];
    int n4 = n / 4;
    int full_blocks = n4 / CHUNK_F4;           // 8640 exactly for this N
    int rem = n4 - full_blocks * CHUNK_F4;
    int grid = full_blocks + ((rem > 0 || (n & 3)) ? 1 : 0);

    hipMemsetAsync(d_ws, 0, 2 * NBINS * SLOTS * sizeof(float), stream);

    qrmse_bins<<<grid, 256, 0, stream>>>(
        (const float4*)yp, (const float4*)yt, yp, yt, g_ss, g_cnt,
        n4, n, full_blocks);
    qrmse_final<<<1, 64, 0, stream>>>(g_ss, g_cnt, out);
}

// Round 5
// 281.066 us; speedup vs baseline: 1.0560x; 1.0299x over previous
//
#include <hip/hip_runtime.h>
#include <math.h>

#define NBINS 4
#define SLOTS 64   // atomic-spread slots per bin

// ws layout: float ss[NBINS][SLOTS], then uint cnt[NBINS][SLOTS]
// bin edges: log1p([0,5,25,50,100]) in float32

// Each block consumes CHUNK_F4 consecutive float4s from EACH input:
// 256 threads x 4 float4s, nontemporal loads (no L3 allocation -> no
// dirty-writeback amplification from the harness's 283MB input restore).
#define CHUNK_F4 1024

typedef float fvec4 __attribute__((ext_vector_type(4)));

__device__ __forceinline__ fvec4 ntload(const fvec4* p) {
    return __builtin_nontemporal_load(p);
}

__global__ __launch_bounds__(256) void qrmse_bins(
    const fvec4* __restrict__ yp4, const fvec4* __restrict__ yt4,
    const float* __restrict__ yp, const float* __restrict__ yt,
    float* __restrict__ g_ss, unsigned int* __restrict__ g_cnt,
    int n4, int n, int full_blocks)
{
    const float B1 = 1.7917594909667969f;   // log1p(5)  in f32
    const float B2 = 3.2580965518951416f;   // log1p(25)
    const float B3 = 3.9318256378173828f;   // log1p(50)
    const float B4 = 4.6151204109191895f;   // log1p(100)

    float ss0 = 0.f, ss1 = 0.f, ss2 = 0.f, ss3 = 0.f;
    unsigned int c0 = 0, c1 = 0, c2 = 0, c3 = 0;

#define ACC(PC, TC)                                          \
    {                                                        \
        float d  = (PC) - (TC);                              \
        float sq = d * d;                                    \
        float tv = (TC);                                     \
        bool b0 = (tv >= 0.f) & (tv < B1);                   \
        bool b1 = (tv >= B1)  & (tv < B2);                   \
        bool b2 = (tv >= B2)  & (tv < B3);                   \
        bool b3 = (tv >= B3)  & (tv < B4);                   \
        ss0 += b0 ? sq : 0.f;  c0 += b0;                     \
        ss1 += b1 ? sq : 0.f;  c1 += b1;                     \
        ss2 += b2 ? sq : 0.f;  c2 += b2;                     \
        ss3 += b3 ? sq : 0.f;  c3 += b3;                     \
    }
#define ACCF4(P, T)                                          \
    { ACC(P.x, T.x); ACC(P.y, T.y); ACC(P.z, T.z); ACC(P.w, T.w); }

    const int tid = threadIdx.x;
    const int b   = blockIdx.x;

    if (b < full_blocks) {
        // guard-free hot path: 8 independent nontemporal 16B loads
        const fvec4* P = yp4 + (size_t)b * CHUNK_F4 + tid;
        const fvec4* T = yt4 + (size_t)b * CHUNK_F4 + tid;
        fvec4 p0 = ntload(P + 0);
        fvec4 p1 = ntload(P + 256);
        fvec4 p2 = ntload(P + 512);
        fvec4 p3 = ntload(P + 768);
        fvec4 t0 = ntload(T + 0);
        fvec4 t1 = ntload(T + 256);
        fvec4 t2 = ntload(T + 512);
        fvec4 t3 = ntload(T + 768);
        ACCF4(p0, t0); ACCF4(p1, t1); ACCF4(p2, t2); ACCF4(p3, t3);
    } else {
        // ragged last block (empty when n4 % CHUNK_F4 == 0)
        for (int i = full_blocks * CHUNK_F4 + tid; i < n4; i += 256) {
            fvec4 p = ntload(yp4 + i);
            fvec4 t = ntload(yt4 + i);
            ACCF4(p, t);
        }
        // scalar tail (n % 4)
        if (tid == 0) {
            for (int i = n4 * 4; i < n; ++i) {
                float pp = yp[i];
                float tt = yt[i];
                ACC(pp, tt);
            }
        }
    }
#undef ACCF4
#undef ACC

    // wave-64 shuffle reduction
    for (int off = 32; off > 0; off >>= 1) {
        ss0 += __shfl_down(ss0, off);
        ss1 += __shfl_down(ss1, off);
        ss2 += __shfl_down(ss2, off);
        ss3 += __shfl_down(ss3, off);
        c0  += __shfl_down(c0,  off);
        c1  += __shfl_down(c1,  off);
        c2  += __shfl_down(c2,  off);
        c3  += __shfl_down(c3,  off);
    }

    __shared__ float        s_ss[4][NBINS];
    __shared__ unsigned int s_cnt[4][NBINS];
    const int lane = tid & 63;
    const int wave = tid >> 6;
    if (lane == 0) {
        s_ss[wave][0] = ss0; s_ss[wave][1] = ss1;
        s_ss[wave][2] = ss2; s_ss[wave][3] = ss3;
        s_cnt[wave][0] = c0; s_cnt[wave][1] = c1;
        s_cnt[wave][2] = c2; s_cnt[wave][3] = c3;
    }
    __syncthreads();

    if (tid == 0) {
        const int slot = b & (SLOTS - 1);
#pragma unroll
        for (int bin = 0; bin < NBINS; ++bin) {
            float bs = s_ss[0][bin] + s_ss[1][bin] + s_ss[2][bin] + s_ss[3][bin];
            unsigned int bc = s_cnt[0][bin] + s_cnt[1][bin] + s_cnt[2][bin] + s_cnt[3][bin];
            atomicAdd(&g_ss[bin * SLOTS + slot], bs);
            atomicAdd(&g_cnt[bin * SLOTS + slot], bc);
        }
    }
}

__global__ __launch_bounds__(64) void qrmse_final(
    const float* __restrict__ g_ss,
    const unsigned int* __restrict__ g_cnt,
    float* __restrict__ out)
{
    const int lane = threadIdx.x;  // 64 lanes, one per slot
    float ssb[NBINS];
    unsigned int cb[NBINS];
#pragma unroll
    for (int b = 0; b < NBINS; ++b) {
        ssb[b] = g_ss[b * SLOTS + lane];
        cb[b]  = g_cnt[b * SLOTS + lane];
    }
    for (int off = 32; off > 0; off >>= 1) {
#pragma unroll
        for (int b = 0; b < NBINS; ++b) {
            ssb[b] += __shfl_down(ssb[b], off);
            cb[b]  += __shfl_down(cb[b],  off);
        }
    }
    if (lane == 0) {
        float wsum = 0.f;
        float mse[NBINS], w[NBINS];
        bool any = false;
#pragma unroll
        for (int b = 0; b < NBINS; ++b) {
            bool present = (cb[b] > 0);
            any |= present;
            float csafe = present ? (float)cb[b] : 1.0f;
            mse[b] = ssb[b] / csafe;
            w[b] = present ? (1.0f / csafe) : 0.0f;
            wsum += w[b];
        }
        float denom = (wsum > 0.f) ? wsum : 1.0f;
        float wmse = 0.f;
#pragma unroll
        for (int b = 0; b < NBINS; ++b) wmse += (w[b] / denom) * mse[b];
        out[0] = any ? sqrtf(wmse + 1e-8f) : 0.0f;
    }
}

extern "C" void kernel_launch(void* const* d_in, const int* in_sizes, int n_in,
                              void* d_out, int out_size, void* d_ws, size_t ws_size,
                              hipStream_t stream) {
    const float* yp = (const float*)d_in[0];
    const float* yt = (const float*)d_in[1];
    float* out = (float*)d_out;

    float* g_ss = (float*)d_ws;                                   // 4*64 floats
    unsigned int* g_cnt = (unsigned int*)d_ws + NBINS * SLOTS;    // 4*64 uints

    int n  = in_sizes[0];
    int n4 = n / 4;
    int full_blocks = n4 / CHUNK_F4;           // 8640 exactly for this N
    int rem = n4 - full_blocks * CHUNK_F4;
    int grid = full_blocks + ((rem > 0 || (n & 3)) ? 1 : 0);

    hipMemsetAsync(d_ws, 0, 2 * NBINS * SLOTS * sizeof(float), stream);

    qrmse_bins<<<grid, 256, 0, stream>>>(
        (const fvec4*)yp, (const fvec4*)yt, yp, yt, g_ss, g_cnt,
        n4, n, full_blocks);
    qrmse_final<<<1, 64, 0, stream>>>(g_ss, g_cnt, out);
}